// Round 18
// baseline (84.987 us; speedup 1.0000x reference)
//
#include <hip/hip_runtime.h>
#include <math.h>

#define L_SEQ 8192
#define B_N   8

typedef float f4v __attribute__((ext_vector_type(4)));

// Workspace layout (float offsets); ~8.7 MB used.
#define QKV_OFF    0                        // [8][512] = 4096 (pre-scaled by 0.125)
#define ROW_OFF    8192                     // [8][512] = 4096
#define QFP_OFF    12288                    // [53][512] = 27136 (qf partials)
#define DPART_OFF  40960                    // [512 slots][8] = 4096
#define YPART_OFF  65536                    // [512 slots][4096] = 2097152

// DPP-fused add: keep + dpp<CTRL>(send).  ctrl: 0xB1=quad xor1, 0x4E=quad xor2,
// 0x128=row_ror:8 (== xor8 within a 16-lane row).
#define DPPADD(keep, send, CTRL) \
    ((keep) + __int_as_float(__builtin_amdgcn_update_dpp(0, __float_as_int(send), (CTRL), 0xF, 0xF, true)))
#define SWZADD(v, PAT) ((v) + __int_as_float(__builtin_amdgcn_ds_swizzle(__float_as_int(v), (PAT))))
#define SWZ(v, PAT)    (__int_as_float(__builtin_amdgcn_ds_swizzle(__float_as_int(v), (PAT))))

// ---- k2: self-contained qf partials: recompute qraw slice in-block, no atomics ----
__global__ __launch_bounds__(512) void k2_qf(const float* __restrict__ poi,
                                             const float* __restrict__ wq1,
                                             const float* __restrict__ bq1,
                                             const float* __restrict__ wq2, float* ws) {
    __shared__ float qr[32];
    int k = blockIdx.x, t = threadIdx.x;
    int i0 = k * 32;
    int cnt = 1683 - i0; if (cnt > 32) cnt = 32;
    if (t < cnt) {
        float a = bq1[0];
#pragma unroll
        for (int j = 0; j < 24; ++j) a += poi[(i0 + t) * 24 + j] * wq1[j];
        qr[t] = a;
    }
    __syncthreads();
    float a = 0.f;
    for (int ii = 0; ii < cnt; ++ii) a += qr[ii] * wq2[(size_t)(i0 + ii) * 512 + t];
    ws[QFP_OFF + k * 512 + t] = a;
}

// ---- k3: qf = bq2 + sum partials; qkvec (pre-scaled); blocks 8-15 also init row=bo ----
__global__ void k3_qkvec(const float* __restrict__ wk, const float* __restrict__ bq2,
                         const float* __restrict__ bo, float* ws) {
    __shared__ float qf[512];
    int t = threadIdx.x, bid = blockIdx.x;
    for (int o = t; o < 512; o += 256) {
        float s = bq2[o];
        for (int k = 0; k < 53; ++k) s += ws[QFP_OFF + k * 512 + o];
        qf[o] = s;
    }
    __syncthreads();
    int idx = bid * 256 + t;
    int h = idx >> 9, c = idx & 511;
    float a = 0.f;
#pragma unroll 8
    for (int e = 0; e < 64; ++e) a += qf[h * 64 + e] * wk[(size_t)c * 512 + h * 64 + e];
    ws[QKV_OFF + idx] = 0.125f * a;
    if (bid >= 8) {
        int b = bid - 8;
        ws[ROW_OFF + b * 512 + t]       = bo[t];
        ws[ROW_OFF + b * 512 + 256 + t] = bo[256 + t];
    }
}

// ---- kF: fused pass, 2 rows/iter, DPP fold-by-head reduce, LANE-CONTIGUOUS loads.
// Each load instr now covers 1KB contiguous (lane i -> float4 i), full 64B sectors,
// vs the old stride-32B half-sector pattern. Dot/fold are layout-invariant (q uses
// the same layout); only the num_s epilogue indexing changes.
// (256,2): only proven no-spill big-regfile config (R7/R12/R14 spill lessons).
__global__ __launch_bounds__(256, 2) void kF(const float* __restrict__ x, float* __restrict__ ws) {
    __shared__ float num_s[4096];
    __shared__ float den_s[8];
    int t = threadIdx.x;
    int lane = t & 63, w = t >> 6;        // 4 waves
    int b = blockIdx.x >> 6, slot = blockIdx.x & 63;
    int wslot = slot * 4 + w;             // 0..255 row streams per batch

    float4 qa[8], qb[8];
    {
        const float4* qg4 = (const float4*)(ws + QKV_OFF);
#pragma unroll
        for (int h = 0; h < 8; ++h) {
            qa[h] = qg4[h * 128 + lane];        // cols 4*lane..4*lane+3
            qb[h] = qg4[h * 128 + 64 + lane];   // cols 256+4*lane..+3
        }
    }

    const int b0 = lane & 1, b1 = (lane >> 1) & 1, b3 = (lane >> 3) & 1;
    float num[8][8] = {{0.f}};
    float den_own = 0.f;                  // running den for head (lane&3)|((lane&8)>>1)

    const float4* xp = (const float4*)(x + (size_t)b * L_SEQ * 512);

    for (int r = wslot; r < L_SEQ; r += 512) {     // 16 iters; rows r and r+256
        int r2 = r + 256;
        float4 xa1 = xp[(size_t)r  * 128 + lane];
        float4 xb1 = xp[(size_t)r  * 128 + 64 + lane];
        float4 xa2 = xp[(size_t)r2 * 128 + lane];
        float4 xb2 = xp[(size_t)r2 * 128 + 64 + lane];

        float p1[8], p2[8];
#pragma unroll
        for (int h = 0; h < 8; ++h) {
            p1[h] = xa1.x * qa[h].x + xa1.y * qa[h].y + xa1.z * qa[h].z + xa1.w * qa[h].w
                  + xb1.x * qb[h].x + xb1.y * qb[h].y + xb1.z * qb[h].z + xb1.w * qb[h].w;
            p2[h] = xa2.x * qa[h].x + xa2.y * qa[h].y + xa2.z * qa[h].z + xa2.w * qa[h].w
                  + xb2.x * qb[h].x + xb2.y * qb[h].y + xb2.z * qb[h].z + xb2.w * qb[h].w;
        }

        // fold level A: head bit0 (xor1, quad_perm)
        float vA0 = DPPADD(b0 ? p1[1] : p1[0], b0 ? p1[0] : p1[1], 0xB1);
        float vA1 = DPPADD(b0 ? p1[3] : p1[2], b0 ? p1[2] : p1[3], 0xB1);
        float vA2 = DPPADD(b0 ? p1[5] : p1[4], b0 ? p1[4] : p1[5], 0xB1);
        float vA3 = DPPADD(b0 ? p1[7] : p1[6], b0 ? p1[6] : p1[7], 0xB1);
        float vB0 = DPPADD(b0 ? p2[1] : p2[0], b0 ? p2[0] : p2[1], 0xB1);
        float vB1 = DPPADD(b0 ? p2[3] : p2[2], b0 ? p2[2] : p2[3], 0xB1);
        float vB2 = DPPADD(b0 ? p2[5] : p2[4], b0 ? p2[4] : p2[5], 0xB1);
        float vB3 = DPPADD(b0 ? p2[7] : p2[6], b0 ? p2[6] : p2[7], 0xB1);
        // fold level B: head bit1 (xor2, quad_perm)
        float uA0 = DPPADD(b1 ? vA1 : vA0, b1 ? vA0 : vA1, 0x4E);
        float uA1 = DPPADD(b1 ? vA3 : vA2, b1 ? vA2 : vA3, 0x4E);
        float uB0 = DPPADD(b1 ? vB1 : vB0, b1 ? vB0 : vB1, 0x4E);
        float uB1 = DPPADD(b1 ? vB3 : vB2, b1 ? vB2 : vB3, 0x4E);
        // fold level C: head bit2 <- lane bit3 (xor8 == row_ror:8 within 16)
        float sA = DPPADD(b3 ? uA1 : uA0, b3 ? uA0 : uA1, 0x128);
        float sB = DPPADD(b3 ? uB1 : uB0, b3 ? uB0 : uB1, 0x128);
        // pure sums over remaining lane bits 2, 4, 5
        sA = SWZADD(sA, 0x101F);  sB = SWZADD(sB, 0x101F);   // xor4
        sA = SWZADD(sA, 0x401F);  sB = SWZADD(sB, 0x401F);   // xor16
        sA += __shfl_xor(sA, 32, 64);
        sB += __shfl_xor(sB, 32, 64);

        float wgA = __expf(sA), wgB = __expf(sB);   // pre-scaled logits; |s| small
        den_own += wgA + wgB;

        // broadcast: head h lives in lane (h&3)|((h&4)<<1) of each 32-group
        float wa[8], wb[8];
        wa[0] = SWZ(wgA,   0); wa[1] = SWZ(wgA,  32); wa[2] = SWZ(wgA,  64); wa[3] = SWZ(wgA,  96);
        wa[4] = SWZ(wgA, 256); wa[5] = SWZ(wgA, 288); wa[6] = SWZ(wgA, 320); wa[7] = SWZ(wgA, 352);
        wb[0] = SWZ(wgB,   0); wb[1] = SWZ(wgB,  32); wb[2] = SWZ(wgB,  64); wb[3] = SWZ(wgB,  96);
        wb[4] = SWZ(wgB, 256); wb[5] = SWZ(wgB, 288); wb[6] = SWZ(wgB, 320); wb[7] = SWZ(wgB, 352);

#pragma unroll
        for (int h = 0; h < 8; ++h) {
            num[h][0] += wa[h] * xa1.x + wb[h] * xa2.x;
            num[h][1] += wa[h] * xa1.y + wb[h] * xa2.y;
            num[h][2] += wa[h] * xa1.z + wb[h] * xa2.z;
            num[h][3] += wa[h] * xa1.w + wb[h] * xa2.w;
            num[h][4] += wa[h] * xb1.x + wb[h] * xb2.x;
            num[h][5] += wa[h] * xb1.y + wb[h] * xb2.y;
            num[h][6] += wa[h] * xb1.z + wb[h] * xb2.z;
            num[h][7] += wa[h] * xb1.w + wb[h] * xb2.w;
        }
    }

    // staged deterministic block reduction across the 4 waves.
    // lane holds cols 4*lane..4*lane+3 (num[h][0..3]) and 256+4*lane..+3 (num[h][4..7]).
    for (int wi = 0; wi < 4; ++wi) {
        if (w == wi) {
#pragma unroll
            for (int h = 0; h < 8; ++h) {
                int base = h * 512 + lane * 4;
                if (wi == 0) {
#pragma unroll
                    for (int j = 0; j < 4; ++j) {
                        num_s[base + j]       = num[h][j];
                        num_s[base + 256 + j] = num[h][4 + j];
                    }
                } else {
#pragma unroll
                    for (int j = 0; j < 4; ++j) {
                        num_s[base + j]       += num[h][j];
                        num_s[base + 256 + j] += num[h][4 + j];
                    }
                }
            }
            if ((lane & 52) == 0) {               // lanes 0,1,2,3,8,9,10,11
                int hh = (lane & 3) | ((lane & 8) >> 1);
                if (wi == 0) den_s[hh] = den_own; else den_s[hh] += den_own;
            }
        }
        __syncthreads();
    }
    // coalesced partial-slot store (no atomics)
    float4* yp4 = (float4*)(ws + YPART_OFF + (size_t)blockIdx.x * 4096);
    const float4* ns4 = (const float4*)num_s;
#pragma unroll
    for (int k = 0; k < 4; ++k) yp4[k * 256 + t] = ns4[k * 256 + t];
    if (t < 8) ws[DPART_OFF + blockIdx.x * 8 + t] = den_s[t];
}

// ---- kVR: merged tail. block=(b,h): den+yn reduce, V chunk = yn_h.wv+bv, then
// row[b,:] += V_chunk.wo (atomic, row init'd to bo by k3). ----
__global__ __launch_bounds__(512) void kVR(const float* __restrict__ wv,
                                           const float* __restrict__ bv,
                                           const float* __restrict__ wo, float* ws) {
    __shared__ float red[512];
    __shared__ float yn_s[512];
    __shared__ float V_s[64];
    int b = blockIdx.x >> 3, h = blockIdx.x & 7;
    int t = threadIdx.x;
    // den[b][h]: 64 slot values
    red[t] = (t < 64) ? ws[DPART_OFF + (size_t)(b * 64 + t) * 8 + h] : 0.f;
    __syncthreads();
#pragma unroll
    for (int off = 32; off >= 1; off >>= 1) {
        if (t < off) red[t] += red[t + off];
        __syncthreads();
    }
    float dinv = 1.f / red[0];
    __syncthreads();
    // yn[h][t]: sum 64 slots
    {
        float s = 0.f;
        const float* yp = ws + YPART_OFF + (size_t)(b * 64) * 4096 + h * 512 + t;
#pragma unroll 8
        for (int sl = 0; sl < 64; ++sl) s += yp[(size_t)sl * 4096];
        yn_s[t] = s * dinv;
    }
    __syncthreads();
    // V chunk: o_local = t&63, c-slice = t>>6
    {
        int ol = t & 63, sl = t >> 6;
        float acc = 0.f;
        const float* yb = yn_s + sl * 64;
        const float* wvp = wv + (size_t)(sl * 64) * 512 + h * 64 + ol;
#pragma unroll 8
        for (int ci = 0; ci < 64; ++ci) acc += yb[ci] * wvp[(size_t)ci * 512];
        red[t] = acc;
    }
    __syncthreads();
    if (t < 64) {
        float acc = bv[h * 64 + t];
#pragma unroll
        for (int sl = 0; sl < 8; ++sl) acc += red[sl * 64 + t];
        V_s[t] = acc;
    }
    __syncthreads();
    // row partial: j = t
    {
        float acc = 0.f;
#pragma unroll 8
        for (int oi = 0; oi < 64; ++oi) acc += V_s[oi] * wo[(size_t)(h * 64 + oi) * 512 + t];
        atomicAdd(ws + ROW_OFF + b * 512 + t, acc);
    }
}

// ---- k9: broadcast out[b,l,:] = row[b,:]  (nontemporal float4 stores) ----
__global__ __launch_bounds__(256) void k9_out(const float* __restrict__ ws, float* __restrict__ out) {
    const f4v* row4 = (const f4v*)(ws + ROW_OFF);
    f4v* out4 = (f4v*)out;
    size_t stride = (size_t)gridDim.x * blockDim.x;
    for (size_t g = (size_t)blockIdx.x * blockDim.x + threadIdx.x; g < 8388608ull; g += stride) {
        int b = (int)(g >> 20);          // 8192 rows * 128 float4/row = 2^20 per batch
        int q = (int)(g & 127);
        f4v v = row4[b * 128 + q];
        __builtin_nontemporal_store(v, &out4[g]);
    }
}

extern "C" void kernel_launch(void* const* d_in, const int* in_sizes, int n_in,
                              void* d_out, int out_size, void* d_ws, size_t ws_size,
                              hipStream_t stream) {
    const float* x   = (const float*)d_in[0];
    const float* poi = (const float*)d_in[1];
    const float* wq1 = (const float*)d_in[2];
    const float* bq1 = (const float*)d_in[3];
    const float* wq2 = (const float*)d_in[4];
    const float* bq2 = (const float*)d_in[5];
    const float* wk  = (const float*)d_in[6];
    const float* bk  = (const float*)d_in[7];
    const float* wv  = (const float*)d_in[8];
    const float* bv  = (const float*)d_in[9];
    const float* wo  = (const float*)d_in[10];
    const float* bo  = (const float*)d_in[11];
    float* ws  = (float*)d_ws;
    float* out = (float*)d_out;
    (void)bk;

    k2_qf<<<53, 512, 0, stream>>>(poi, wq1, bq1, wq2, ws);
    k3_qkvec<<<16, 256, 0, stream>>>(wk, bq2, bo, ws);
    kF<<<512, 256, 0, stream>>>(x, ws);
    kVR<<<64, 512, 0, stream>>>(wv, bv, wo, ws);
    k9_out<<<2048, 256, 0, stream>>>(ws, out);
}